// Round 2
// baseline (140153.235 us; speedup 1.0000x reference)
//
#include <hip/hip_runtime.h>
#include <hip/hip_bf16.h>
#include <math.h>

// ============================================================================
// RNNDecoder v2: persistent kernel, fp32 VALU everywhere (argmax-trajectory
// fidelity), runtime input-dtype detection (bf16 vs f32 via embed PAD row),
// 128 blocks; 16 same-XCD blocks j-split each group's GRU; attention/cc/
// logits per-row local. 2 sync flags per step.
// ============================================================================

typedef unsigned short u16;
typedef unsigned int u32;
typedef float f4 __attribute__((ext_vector_type(4)));

#define NB 128
#define NT 1024
#define Ln 500
#define Hn 512
#define LDn 256
#define UDn 128
#define Vn 33
#define Tn 500
#define SENT_V 0x9E3779B1u

// ---- workspace u32 offsets ----
#define W_FLG   0u         // [500][8][8] counters
#define W_INITC 32000u
#define W_SENT  32001u
#define W_WHH   32064u     // f32 [1536][512]  W_hh natural
#define W_GEM   818496u    // f32 [33][1536]   embed@W_ih^T + b_ih
#define W_CWT   869184u    // f32 [512k][512j] catW left, transposed
#define W_M2T   1131328u   // f32 [128u][512j] catW_right@memW, transposed
#define W_MW    1196864u   // f32 [512k][128u] mem_W
#define W_MB    1262400u   // f32 [512]
#define W_BHH   1262912u   // f32 [1536]
#define W_CB    1264448u   // f32 [512] cat_b + catWr@mem_b
#define W_OWT   1264960u   // f32 [512][34] out_W^T padded
#define W_OB    1282368u   // f32 [64]
#define W_H     1282432u   // f32 [2][128][512] h double buffer
#define W_TOK   1413504u   // int [128]
#define W_END   1413632u

// ---- LDS byte offsets ----
#define L_A1   0        // 16KB arena: Apart[16][32][8] | Bpart[8][128]@0 | ccpart[2][512]@8192
#define L_G2   16384    // 6KB arena: gh3[3][16][32] | ss@0(2048) es@2048(2048) cuv@4096(512)
#define L_HOWN 22528    // f32[512]
#define L_PS   24576    // f32[128]
#define L_CCS  25088    // f32[512]
#define L_LG   27136    // f32[16*34]
#define L_MISC 29312    // f32[16]: [0]=s0 [1]=inv_sum
#define LDS_SZ 29376

__device__ __forceinline__ float b2f(u16 v) {
  u32 x = ((u32)v) << 16; float f; __builtin_memcpy(&f, &x, 4); return f;
}
__device__ __forceinline__ float bitsf(u32 x) {
  float f; __builtin_memcpy(&f, &x, 4); return f;
}
__device__ __forceinline__ u16 f2b(float f) {  // RNE
  u32 x; __builtin_memcpy(&x, &f, 4);
  x += 0x7fffu + ((x >> 16) & 1u);
  return (u16)(x >> 16);
}
// mode==1: buffer holds bf16; mode==0: fp32
__device__ __forceinline__ float ldv(const void* p, int i, int mode) {
  return mode ? b2f(((const u16*)p)[i]) : ((const float*)p)[i];
}
__device__ __forceinline__ u32 aload(u32* p) {
  return __hip_atomic_load(p, __ATOMIC_ACQUIRE, __HIP_MEMORY_SCOPE_AGENT);
}
__device__ __forceinline__ void waitGe(u32* p, u32 tgt) {
  while (aload(p) < tgt) __builtin_amdgcn_s_sleep(4);
}
__device__ __forceinline__ void arrive(u32* p) {
  __hip_atomic_fetch_add(p, 1u, __ATOMIC_RELEASE, __HIP_MEMORY_SCOPE_AGENT);
}
__device__ __forceinline__ void astore(u32* p, u32 v) {
  __hip_atomic_store(p, v, __ATOMIC_RELEASE, __HIP_MEMORY_SCOPE_AGENT);
}

extern "C" __global__ void __launch_bounds__(1024)
rnn_v2(const void* latent, const void* ulat, const void* embd,
       const void* hidW, const void* hidb, const void* memW, const void* memb,
       const void* Wih, const void* Whh, const void* bih, const void* bhh,
       const void* catW, const void* catb, const void* outW, const void* outb,
       void* out, u32* ws) {
  __shared__ char lds[LDS_SZ];
  __shared__ u32 s_det;
  const int tid = threadIdx.x, blk = blockIdx.x;
  const int wv = tid >> 6, lane = tid & 63;
  const int bt = blk & 7;   // group id (same-XCD members share blk&7)
  const int m  = blk >> 3;  // member index 0..15; owner row = blk
  const int gtid = blk * NT + tid;

  // ---- dtype detection: embed row PAD=1 is zero; bytes [1024,2048) are that
  // row iff bf16. Computed per-block, deterministic, no sync needed.
  if (tid == 0) s_det = 0u;
  __syncthreads();
  if (tid < 256) {
    u32 v = ((const u32*)embd)[256 + tid];
    if (v) atomicOr(&s_det, 1u);
  }
  __syncthreads();
  const int mode = (s_det == 0u) ? 1 : 0;  // 1 = bf16 inputs, 0 = f32 inputs

  float* WhhF  = (float*)(ws + W_WHH);
  float* GEM   = (float*)(ws + W_GEM);
  float* cWT   = (float*)(ws + W_CWT);
  float* M2T   = (float*)(ws + W_M2T);
  float* mWF   = (float*)(ws + W_MW);
  float* mBF   = (float*)(ws + W_MB);
  float* bhhF  = (float*)(ws + W_BHH);
  float* cbF   = (float*)(ws + W_CB);
  float* oWT   = (float*)(ws + W_OWT);
  float* obF   = (float*)(ws + W_OB);
  float* hbuf  = (float*)(ws + W_H);
  int*   tokb  = (int*)(ws + W_TOK);

  float* Apart = (float*)(lds + L_A1);          // [16][32][8]
  float* Bpart = (float*)(lds + L_A1);          // [8][128] (time-disjoint)
  float* ccp   = (float*)(lds + L_A1 + 8192);   // [2][512]
  float* gh3   = (float*)(lds + L_G2);          // [3][16][32]
  float* ss    = (float*)(lds + L_G2);          // [512]  (phase-B reuse)
  float* es    = (float*)(lds + L_G2 + 2048);   // [512]
  float* cuv   = (float*)(lds + L_G2 + 4096);   // [128]
  float* hown  = (float*)(lds + L_HOWN);
  float* ps    = (float*)(lds + L_PS);
  float* ccs   = (float*)(lds + L_CCS);
  float* lgs   = (float*)(lds + L_LG);
  float* misc  = (float*)(lds + L_MISC);

  // ======================= one-time init (fp32 weights in ws) ===============
  for (int i = gtid; i < 32000; i += NB * NT) ws[W_FLG + i] = 0u;       // flags
  for (int i = gtid; i < 131072; i += NB * NT) ws[W_H + i] = 0u;        // h zero
  if (gtid < 128) tokb[gtid] = 0;                                       // SOS
  for (int i = gtid; i < 786432; i += NB * NT) WhhF[i] = ldv(Whh, i, mode);
  for (int i = gtid; i < 65536; i += NB * NT) mWF[i] = ldv(memW, i, mode);
  if (gtid < 512) mBF[gtid] = ldv(memb, gtid, mode);
  for (int i = gtid; i < 1536; i += NB * NT) bhhF[i] = ldv(bhh, i, mode);
  for (int i = gtid; i < 17408; i += NB * NT) {        // out_W^T [512][34]
    int j = i / 34, v = i - j * 34;
    oWT[i] = (v < Vn) ? ldv(outW, v * Hn + j, mode) : 0.f;
  }
  if (gtid < 64) obF[gtid] = (gtid < Vn) ? ldv(outb, gtid, mode) : 0.f;
  for (int i = gtid; i < 262144; i += NB * NT) {       // catW-left^T [k][j]
    int k = i >> 9, j = i & 511;
    cWT[i] = ldv(catW, j * 1024 + k, mode);
  }
  if (gtid < 50688) {                                  // GEM = embed@Wih^T+bih
    int v = gtid / 1536, j = gtid - v * 1536;
    float a = ldv(bih, j, mode);
    for (int k = 0; k < Hn; k++)
      a += ldv(embd, v * Hn + k, mode) * ldv(Wih, j * Hn + k, mode);
    GEM[gtid] = a;
  }
  if (gtid < 65536) {                                  // M2^T[u][j]
    int u = gtid >> 9, j = gtid & 511;
    float a = 0.f;
    for (int h = 0; h < Hn; h++)
      a += ldv(catW, j * 1024 + 512 + h, mode) * ldv(memW, h * UDn + u, mode);
    M2T[gtid] = a;
  }
  if (gtid < 512) {                                    // cbias
    int j = gtid;
    float a = ldv(catb, j, mode);
    for (int h = 0; h < Hn; h++)
      a += ldv(catW, j * 1024 + 512 + h, mode) * ldv(memb, h, mode);
    cbF[j] = a;
  }
  if (gtid < 65536) {                                  // h0 -> parity 0
    int b = gtid >> 9, k = gtid & 511;
    float a = ldv(hidb, k, mode);
    for (int q = 0; q < LDn; q++)
      a += ldv(latent, b * LDn + q, mode) * ldv(hidW, k * LDn + q, mode);
    hbuf[b * Hn + k] = a;
  }
  __threadfence();
  __syncthreads();
  if (tid == 0) {  // poison-agnostic device barrier
    if (blk == 0) {
      __hip_atomic_store(ws + W_INITC, 0u, __ATOMIC_RELAXED, __HIP_MEMORY_SCOPE_AGENT);
      astore(ws + W_SENT, SENT_V);
    }
    while (aload(ws + W_SENT) != SENT_V) __builtin_amdgcn_s_sleep(8);
    arrive(ws + W_INITC);
    waitGe(ws + W_INITC, NB);
  }
  __syncthreads();

  const int jj = tid & 31;        // phase-A j within member share
  const int kc = (tid >> 5) & 7;  // k chunk (64)
  const int rw = tid >> 8;        // row quad

  // ======================= 500 decode steps =================================
  for (int t = 0; t < Tn; t++) {
    u32* line = ws + W_FLG + ((unsigned)(t * 8 + bt)) * 8u;  // [0]=A(16) [1]=D(16)
    const float* hc = hbuf + (t & 1) * 65536;
    float* hnw = hbuf + ((t & 1) ^ 1) * 65536;

    // ---- A-wait: previous step fully done for this group --------------------
    if (t > 0 && wv == 0) {
      u32* lineP = ws + W_FLG + ((unsigned)((t - 1) * 8 + bt)) * 8u;
      waitGe(lineP + 1, 16u);
    }
    __syncthreads();

    // ---- phase A: GRU j-split; member covers j = m*32 + [0,32) per gate -----
    for (int g = 0; g < 3; g++) {
      const float* wrow = WhhF + (size_t)(g * 512 + m * 32 + jj) * 512 + kc * 64;
      const float* h0p = hc + ((rw * 4 + 0) * 8 + bt) * Hn + kc * 64;
      const float* h1p = hc + ((rw * 4 + 1) * 8 + bt) * Hn + kc * 64;
      const float* h2p = hc + ((rw * 4 + 2) * 8 + bt) * Hn + kc * 64;
      const float* h3p = hc + ((rw * 4 + 3) * 8 + bt) * Hn + kc * 64;
      float a0 = 0.f, a1 = 0.f, a2 = 0.f, a3 = 0.f;
#pragma unroll
      for (int k4 = 0; k4 < 16; k4++) {
        const f4 w = *(const f4*)(wrow + k4 * 4);
        f4 x;
        x = *(const f4*)(h0p + k4 * 4);
        a0 = fmaf(w.x, x.x, fmaf(w.y, x.y, fmaf(w.z, x.z, fmaf(w.w, x.w, a0))));
        x = *(const f4*)(h1p + k4 * 4);
        a1 = fmaf(w.x, x.x, fmaf(w.y, x.y, fmaf(w.z, x.z, fmaf(w.w, x.w, a1))));
        x = *(const f4*)(h2p + k4 * 4);
        a2 = fmaf(w.x, x.x, fmaf(w.y, x.y, fmaf(w.z, x.z, fmaf(w.w, x.w, a2))));
        x = *(const f4*)(h3p + k4 * 4);
        a3 = fmaf(w.x, x.x, fmaf(w.y, x.y, fmaf(w.z, x.z, fmaf(w.w, x.w, a3))));
      }
      Apart[((rw * 4 + 0) * 32 + jj) * 8 + kc] = a0;
      Apart[((rw * 4 + 1) * 32 + jj) * 8 + kc] = a1;
      Apart[((rw * 4 + 2) * 32 + jj) * 8 + kc] = a2;
      Apart[((rw * 4 + 3) * 32 + jj) * 8 + kc] = a3;
      __syncthreads();
      if (tid < 512) {
        const int mm = tid >> 5, jr = tid & 31;
        float s = 0.f;
#pragma unroll
        for (int c = 0; c < 8; c++) s += Apart[(mm * 32 + jr) * 8 + c];
        gh3[g * 512 + mm * 32 + jr] = s + bhhF[g * 512 + m * 32 + jr];
      }
      __syncthreads();
    }
    if (tid < 512) {  // gate nonlinearity + h update for 16 group rows
      const int mm = tid >> 5, jr = tid & 31;
      const int jglob = m * 32 + jr;
      const int bg = mm * 8 + bt;
      int tk = tokb[bg];
      if ((unsigned)tk > 32u) tk = 0;  // defensive clamp
      const float giR = GEM[tk * 1536 + jglob];
      const float giZ = GEM[tk * 1536 + 512 + jglob];
      const float giN = GEM[tk * 1536 + 1024 + jglob];
      const float r = 1.f / (1.f + expf(-(giR + gh3[0 * 512 + mm * 32 + jr])));
      const float z = 1.f / (1.f + expf(-(giZ + gh3[1 * 512 + mm * 32 + jr])));
      const float n = tanhf(giN + r * gh3[2 * 512 + mm * 32 + jr]);
      const float hv = hc[bg * Hn + jglob];
      hnw[bg * Hn + jglob] = (1.f - z) * n + z * hv;
    }
    __syncthreads();
    if (tid == 0) { __threadfence(); arrive(line + 0); }

    // ---- B-wait: full h_new for this group --------------------------------
    if (wv == 0) waitGe(line + 0, 16u);
    __syncthreads();
    if (tid < Hn) hown[tid] = hnw[blk * Hn + tid];
    __syncthreads();

    // ---- attention: p = memW^T h_new --------------------------------------
    {
      const int u = tid & 127, c8 = tid >> 7;
      float a = 0.f;
      for (int k = c8 * 64; k < c8 * 64 + 64; k++)
        a = fmaf(mWF[k * UDn + u], hown[k], a);
      Bpart[c8 * UDn + u] = a;
    }
    __syncthreads();
    if (tid < 128) {
      float s = 0.f;
#pragma unroll
      for (int c = 0; c < 8; c++) s += Bpart[c * UDn + tid];
      ps[tid] = s;
    } else if (tid < 192) {  // wave 2: s0 = h_new . mem_b
      const int ln = tid - 128;
      float a = 0.f;
#pragma unroll
      for (int i = 0; i < 8; i++) { int k = ln + i * 64; a = fmaf(hown[k], mBF[k], a); }
      for (int o = 32; o; o >>= 1) a += __shfl_down(a, o);
      if (ln == 0) misc[0] = a;
    }
    __syncthreads();

    // ---- scores[l] = p . ul[blk][l] + s0  (half-row per lane) -------------
    {
      const int l = (wv << 5) + (lane >> 1), uh = lane & 1;
      float val = 0.f;
      if (l < Ln) {
        if (mode) {
          const u32* q = (const u32*)ulat + ((size_t)blk * Ln + l) * 64 + uh * 32;
          for (int i = 0; i < 32; i++) {
            const u32 d = q[i];
            val = fmaf(bitsf(d << 16), ps[uh * 64 + i * 2], val);
            val = fmaf(bitsf(d & 0xffff0000u), ps[uh * 64 + i * 2 + 1], val);
          }
        } else {
          const float* q = (const float*)ulat + ((size_t)blk * Ln + l) * UDn + uh * 64;
          for (int i = 0; i < 64; i++) val = fmaf(q[i], ps[uh * 64 + i], val);
        }
      }
      const float v2 = __shfl_down(val, 1);
      if ((lane & 1) == 0 && l < Ln) ss[l] = val + v2 + misc[0];
    }
    __syncthreads();
    if (wv == 0) {  // softmax stats over 500
      float mx = -3.4e38f;
      for (int i = 0; i < 8; i++) {
        int l = lane + (i << 6);
        if (l < Ln) mx = fmaxf(mx, ss[l]);
      }
      for (int o = 32; o; o >>= 1) mx = fmaxf(mx, __shfl_xor(mx, o));
      float sum = 0.f;
      for (int i = 0; i < 8; i++) {
        int l = lane + (i << 6);
        if (l < Ln) { float e = expf(ss[l] - mx); es[l] = e; sum += e; }
      }
      for (int o = 32; o; o >>= 1) sum += __shfl_xor(sum, o);
      if (lane == 0) misc[1] = 1.f / sum;
    }
    __syncthreads();

    // ---- cu[u] = inv * sum_l es[l] * ul[l][u] -----------------------------
    {
      const int u = tid & 127, lc = tid >> 7;
      const int lend = (lc * 64 + 64 < Ln) ? lc * 64 + 64 : Ln;
      float a = 0.f;
      if (mode) {
        const u16* q = (const u16*)ulat + ((size_t)blk * Ln) * UDn + u;
        for (int l = lc * 64; l < lend; l++) a = fmaf(es[l], b2f(q[l * UDn]), a);
      } else {
        const float* q = (const float*)ulat + ((size_t)blk * Ln) * UDn + u;
        for (int l = lc * 64; l < lend; l++) a = fmaf(es[l], q[l * UDn], a);
      }
      Bpart[lc * UDn + u] = a;
    }
    __syncthreads();
    if (tid < 128) {
      float s = 0.f;
#pragma unroll
      for (int c = 0; c < 8; c++) s += Bpart[c * UDn + tid];
      cuv[tid] = s * misc[1];
    }
    __syncthreads();

    // ---- cc = tanh(catWl.h + M2.cu + cbias) -------------------------------
    {
      const int j = tid & 511, hf = tid >> 9;
      float a = 0.f;
      for (int k = hf * 256; k < hf * 256 + 256; k++)
        a = fmaf(cWT[k * Hn + j], hown[k], a);
      for (int u = hf * 64; u < hf * 64 + 64; u++)
        a = fmaf(M2T[u * Hn + j], cuv[u], a);
      ccp[hf * Hn + j] = a;
    }
    __syncthreads();
    if (tid < 512) ccs[tid] = tanhf(ccp[tid] + ccp[512 + tid] + cbF[tid]);
    __syncthreads();

    // ---- logits + argmax + output -----------------------------------------
    if (lane < Vn) {
      const int j0 = wv << 5;
      float part = 0.f;
#pragma unroll
      for (int q = 0; q < 32; q++) part = fmaf(ccs[j0 + q], oWT[(j0 + q) * 34 + lane], part);
      lgs[wv * 34 + lane] = part;
    }
    __syncthreads();
    if (wv == 0) {
      float lg = -3.4e38f;
      int idx = 0;
      if (lane < Vn) {
        float s = obF[lane];
#pragma unroll
        for (int w2 = 0; w2 < 16; w2++) s += lgs[w2 * 34 + lane];
        if (mode) ((u16*)out)[(size_t)blk * (Vn * Ln) + lane * Ln + t] = f2b(s);
        else ((float*)out)[(size_t)blk * (Vn * Ln) + lane * Ln + t] = s;
        lg = s;
        idx = lane;
      }
      for (int o = 32; o; o >>= 1) {  // np argmax: first max wins
        const float ov = __shfl_down(lg, o);
        const int oi = __shfl_down(idx, o);
        if (ov > lg || (ov == lg && oi < idx)) { lg = ov; idx = oi; }
      }
      if (lane == 0) tokb[blk] = idx;
      __threadfence();
      if (lane == 0) arrive(line + 1);
    }
  }
}

extern "C" void kernel_launch(void* const* d_in, const int* in_sizes, int n_in,
                              void* d_out, int out_size, void* d_ws, size_t ws_size,
                              hipStream_t stream) {
  (void)in_sizes; (void)n_in; (void)out_size;
  if (ws_size < (size_t)W_END * 4) return;  // needs ~5.7 MB scratch
  hipLaunchKernelGGL(rnn_v2, dim3(NB), dim3(NT), 0, stream,
                     d_in[0],   // latent
                     d_in[1],   // upsampled_latent
                     d_in[3],   // embed (d_in[2]=target unused in eval)
                     d_in[4],   // hid_W
                     d_in[5],   // hid_b
                     d_in[6],   // mem_W
                     d_in[7],   // mem_b
                     d_in[8],   // W_ih
                     d_in[9],   // W_hh
                     d_in[10],  // b_ih
                     d_in[11],  // b_hh
                     d_in[12],  // cat_W
                     d_in[13],  // cat_b
                     d_in[14],  // out_W
                     d_in[15],  // out_b
                     d_out, (u32*)d_ws);
}